// Round 9
// baseline (348.980 us; speedup 1.0000x reference)
//
#include <hip/hip_runtime.h>

// Problem constants
#define BB 8
#define NN 1024
#define CC 768
#define HH 12
#define HD 64
#define RR 16
#define MM (BB * NN)   // 8192 tokens
#define WSZ (CC * CC)  // 589824 elements per weight matrix
#define NT (NN / 64)   // 16 kv tiles

// softmax scale folded with log2(e) for exp2f: HD^-0.5 * 1.4426950408889634
// (folded into the q-store of gemm_qkv; attn works in the scaled domain)
#define KSC 0.18033688011112042f

typedef short bf16x8 __attribute__((ext_vector_type(8)));
typedef short bf16x4 __attribute__((ext_vector_type(4)));
typedef float f32x4 __attribute__((ext_vector_type(4)));

__device__ __forceinline__ unsigned short f2bf(float f) {
    unsigned u = __builtin_bit_cast(unsigned, f);
    unsigned r = (u + 0x7FFFu + ((u >> 16) & 1u)) >> 16;
    return (unsigned short)r;
}
__device__ __forceinline__ float bf2f(unsigned short s) {
    return __builtin_bit_cast(float, ((unsigned)s) << 16);
}

// single-instruction exp2 (v_exp_f32); inputs here are finite, underflow->0 ok
__device__ __forceinline__ float fast_exp2(float x) {
#if __has_builtin(__builtin_amdgcn_exp2f)
    return __builtin_amdgcn_exp2f(x);
#else
    return exp2f(x);
#endif
}

// packed f32x2 -> bf16x2 (RNE, same as f2bf): dst[15:0]=a, dst[31:16]=b
__device__ __forceinline__ unsigned cvt_pk_bf16(float a, float b) {
    unsigned r;
    asm("v_cvt_pk_bf16_f32 %0, %1, %2" : "=v"(r) : "v"(a), "v"(b));
    return r;
}

// async 16B global -> LDS (DMA; LDS dest is wave-uniform base + lane*16)
__device__ __forceinline__ void gload16(const void* g, void* l) {
    __builtin_amdgcn_global_load_lds(
        (const __attribute__((address_space(1))) unsigned int*)g,
        (__attribute__((address_space(3))) unsigned int*)l, 16, 0, 0);
}

// counted-wait primitives (T4): never drain fresh loads inside the loop
__device__ __forceinline__ void wait_vm0_barrier() {
    asm volatile("s_waitcnt vmcnt(0)" ::: "memory");
    __builtin_amdgcn_s_barrier();
}

// ---------------------------------------------------------------------------
// prep_w: We_z = W_z + bw[z] * la_z @ lb_z  (z<3), We_3 = Wp.
// Output TRANSPOSED bf16 hi/lo: Wt[z][n][k]. (lo used only by proj's Wp.)
// ---------------------------------------------------------------------------
__global__ __launch_bounds__(256) void prep_w(
    const float* __restrict__ Wq, const float* __restrict__ Wk,
    const float* __restrict__ Wv, const float* __restrict__ Wp,
    const float* __restrict__ la_q, const float* __restrict__ lb_q,
    const float* __restrict__ la_k, const float* __restrict__ lb_k,
    const float* __restrict__ la_v, const float* __restrict__ lb_v,
    const float* __restrict__ bw, short* __restrict__ wt_hi,
    short* __restrict__ wt_lo) {
    __shared__ float laS[64][16];
    __shared__ float lbS[16][64];
    __shared__ float T[64][65];

    const int z = blockIdx.z;
    const int k0 = blockIdx.y * 64, n0 = blockIdx.x * 64;
    const int tid = threadIdx.x;

    const float* W = (z == 0) ? Wq : (z == 1) ? Wk : (z == 2) ? Wv : Wp;
    const float* la = (z == 0) ? la_q : (z == 1) ? la_k : la_v;
    const float* lb = (z == 0) ? lb_q : (z == 1) ? lb_k : lb_v;
    const float bwz = (z < 3) ? bw[z] : 0.f;

    if (z < 3) {
        #pragma unroll
        for (int e = 0; e < 4; ++e) {
            int idx = tid + 256 * e;
            laS[idx >> 4][idx & 15] = la[(size_t)(k0 + (idx >> 4)) * RR + (idx & 15)];
            lbS[idx >> 6][idx & 63] = lb[(size_t)(idx >> 6) * CC + n0 + (idx & 63)];
        }
    }
    __syncthreads();

    #pragma unroll
    for (int e = 0; e < 16; ++e) {
        int idx = tid + 256 * e;
        int row = idx >> 6, col = idx & 63;
        float v = W[(size_t)(k0 + row) * CC + n0 + col];
        if (z < 3) {
            float s = 0.f;
            #pragma unroll
            for (int r = 0; r < 16; ++r) s += laS[row][r] * lbS[r][col];
            v += bwz * s;
        }
        T[row][col] = v;
    }
    __syncthreads();

    short* oh = wt_hi + (size_t)z * WSZ;
    short* ol = wt_lo + (size_t)z * WSZ;
    #pragma unroll
    for (int e = 0; e < 16; ++e) {
        int idx = tid + 256 * e;
        int nrow = idx >> 6, kcol = idx & 63;
        float v = T[kcol][nrow];
        unsigned short hi = f2bf(v);
        unsigned short lo = f2bf(v - bf2f(hi));
        size_t off = (size_t)(n0 + nrow) * CC + k0 + kcol;
        oh[off] = (short)hi;
        ol[off] = (short)lo;
    }
}

// ---------------------------------------------------------------------------
// prep_cvt: fp32 -> bf16 (hi only; QKV GEMM runs plain bf16).
// ---------------------------------------------------------------------------
__global__ __launch_bounds__(256) void prep_cvt(const float* __restrict__ src,
                                                short* __restrict__ hi, int n4) {
    int i = blockIdx.x * 256 + threadIdx.x;
    const int stride = gridDim.x * 256;
    for (; i < n4; i += stride) {
        f32x4 v = ((const f32x4*)src)[i];
        bf16x4 h;
        #pragma unroll
        for (int c = 0; c < 4; ++c) h[c] = (short)f2bf(v[c]);
        ((bf16x4*)hi)[i] = h;
    }
}

// ---------------------------------------------------------------------------
// Plain bf16 MFMA GEMM core (QKV), counted-wait pipeline:
// per iter: vmcnt(0) [waits the stage issued ONE FULL iter ago] -> s_barrier
// -> issue stage(t+1) into the buffer freed by compute(t-1) -> compute t.
// LDS 2x16KB -> 5 blocks/CU. Frag-major layout: element f (0..511) of each
// 128x32 sub-tile at f*16B, f=(row>>4)*64 + (kcol>>3)*16 + (row&15).
// ---------------------------------------------------------------------------
__device__ __forceinline__ void stage_plain(const short* __restrict__ gA,
                                            const short* __restrict__ gB,
                                            int rowA0, int rowB0, int kt,
                                            short* Lb, int tid) {
    const int fr = ((tid >> 6) << 4) | (tid & 15);  // row offset within tile
    const int kc = ((tid >> 4) & 3) * 8 + kt;       // col (shorts)
    const size_t ga0 = (size_t)(rowA0 + fr) * CC + kc;
    const size_t gb0 = (size_t)(rowB0 + fr) * CC + kc;
    short* d0 = Lb + tid * 8;
    short* d1 = Lb + (tid + 256) * 8;
    gload16(gA + ga0, d0);
    gload16(gA + ga0 + (size_t)64 * CC, d1);
    gload16(gB + gb0, d0 + 4096);
    gload16(gB + gb0 + (size_t)64 * CC, d1 + 4096);
}

__device__ __forceinline__ void gemm_core_plain(const short* __restrict__ gA,
                                                int rowA0,
                                                const short* __restrict__ gB,
                                                int rowB0, short (*L)[8192],
                                                f32x4 acc[4][4]) {
    const int tid = threadIdx.x, lane = tid & 63, w = tid >> 6;
    const int wm = w >> 1, wn = w & 1;
    stage_plain(gA, gB, rowA0, rowB0, 0, L[0], tid);
    for (int ki = 0; ki < 24; ++ki) {
        wait_vm0_barrier();  // tile ki ready for ALL waves; buf (ki-1)&1 free
        if (ki < 23)
            stage_plain(gA, gB, rowA0, rowB0, (ki + 1) * 32, L[(ki + 1) & 1],
                        tid);  // lands during compute of tile ki (full overlap)
        const short* Lb = L[ki & 1];
        bf16x8 ah[4], bh[4];
        #pragma unroll
        for (int i = 0; i < 4; ++i)
            ah[i] = *(const bf16x8*)(Lb + (wm * 4 + i) * 512 + lane * 8);
        #pragma unroll
        for (int j = 0; j < 4; ++j)
            bh[j] = *(const bf16x8*)(Lb + 4096 + (wn * 4 + j) * 512 + lane * 8);
        #pragma unroll
        for (int i = 0; i < 4; ++i)
            #pragma unroll
            for (int j = 0; j < 4; ++j)
                acc[i][j] = __builtin_amdgcn_mfma_f32_16x16x32_bf16(
                    ah[i], bh[j], acc[i][j], 0, 0, 0);
        // no end-of-iter barrier: next iter's vmcnt+barrier provides ordering
    }
}

// ---------------------------------------------------------------------------
// gemm_qkv (plain bf16): z=0/1 -> q/k bf16 [B,H,N,HD]; z=2 -> V^T [B,H,HD,N].
// q pre-scaled by KSC so attn needs no per-element scale multiply.
// ---------------------------------------------------------------------------
__global__ __launch_bounds__(256, 5) void gemm_qkv(
    const short* __restrict__ xh, const short* __restrict__ wth,
    short* __restrict__ qb, short* __restrict__ kb, short* __restrict__ vtb) {
    __shared__ __align__(16) short L[2][8192];  // 32 KiB -> 5 blocks/CU

    // bijective XCD swizzle over the 1152-wg grid (1152 % 8 == 0)
    int flat = blockIdx.x + 6 * blockIdx.y + 384 * blockIdx.z;
    int swz = (flat & 7) * 144 + (flat >> 3);
    int z = swz / 384;
    int rem = swz - z * 384;
    int by = rem / 6, bx = rem - by * 6;
    const int m0 = by * 128, c0 = bx * 128;

    const short* wzh = wth + (size_t)z * WSZ;

    f32x4 acc[4][4];
    const f32x4 z4 = {0.f, 0.f, 0.f, 0.f};
    #pragma unroll
    for (int i = 0; i < 4; ++i)
        #pragma unroll
        for (int j = 0; j < 4; ++j) acc[i][j] = z4;

    const int lane = threadIdx.x & 63, w = threadIdx.x >> 6;
    const int wm = w >> 1, wn = w & 1, p = lane & 15, g = lane >> 4;

    if (z < 2) {
        gemm_core_plain(xh, m0, wzh, c0, L, acc);
        short* dst = (z == 0) ? qb : kb;
        const float scl = (z == 0) ? KSC : 1.0f;  // fold softmax scale into q
        #pragma unroll
        for (int i = 0; i < 4; ++i) {
            #pragma unroll
            for (int r = 0; r < 4; ++r) {
                int m = m0 + wm * 64 + i * 16 + 4 * g + r;
                int b = m >> 10, n = m & 1023;
                #pragma unroll
                for (int j = 0; j < 4; ++j) {
                    int c = c0 + wn * 64 + j * 16 + p;
                    int h = c >> 6, d = c & 63;
                    dst[(((size_t)(b * HH + h)) * NN + n) * HD + d] =
                        (short)f2bf(acc[i][j][r] * scl);
                }
            }
        }
    } else {
        gemm_core_plain(wzh, c0, xh, m0, L, acc);
        #pragma unroll
        for (int i = 0; i < 4; ++i) {
            #pragma unroll
            for (int r = 0; r < 4; ++r) {
                int c = c0 + wm * 64 + i * 16 + 4 * g + r;
                int h = c >> 6, d = c & 63;
                #pragma unroll
                for (int j = 0; j < 4; ++j) {
                    int m = m0 + wn * 64 + j * 16 + p;
                    int b = m >> 10, n = m & 1023;
                    vtb[(((size_t)(b * HH + h)) * HD + d) * NN + n] =
                        (short)f2bf(acc[i][j][r]);
                }
            }
        }
    }
}

// ---------------------------------------------------------------------------
// attn: bf16 MFMA flash attention, counted-wait single-barrier loop.
// Per iter: vmcnt(0)+barrier (tile t ready) -> stage(t+1) -> QK/softmax/PV.
// Q tile LDS reused as per-wave P tile. 40KB LDS -> 4 blocks/CU.
// ---------------------------------------------------------------------------
__device__ __forceinline__ void stage_kv(const short* __restrict__ kp,
                                         const short* __restrict__ vp, int j0,
                                         short* Kd, short* Vd, int tid) {
    const int pp = tid & 15;
    const int kc = ((tid >> 4) & 3) * 8 + ((tid >> 6) & 1) * 32;
    const int r0 = tid >> 7;  // 0..1; second element uses r0+2
    gload16(kp + (size_t)(j0 + r0 * 16 + pp) * HD + kc, Kd + tid * 8);
    gload16(kp + (size_t)(j0 + (r0 + 2) * 16 + pp) * HD + kc, Kd + (tid + 256) * 8);
    gload16(vp + (size_t)(r0 * 16 + pp) * NN + j0 + kc, Vd + tid * 8);
    gload16(vp + (size_t)((r0 + 2) * 16 + pp) * NN + j0 + kc, Vd + (tid + 256) * 8);
}

__global__ __launch_bounds__(256, 4) void attn(const short* __restrict__ qb,
                                               const short* __restrict__ kb,
                                               const short* __restrict__ vtb,
                                               short* __restrict__ aoh,
                                               short* __restrict__ aol) {
    __shared__ __align__(16) short QP[4096];   // Q tile, then P tiles
    __shared__ __align__(16) short Kb[2][4096];
    __shared__ __align__(16) short Vb[2][4096];

    // XCD swizzle: 12 consecutive (b,h) per XCD -> KV L2-resident
    int flat = blockIdx.x + 16 * blockIdx.y;  // 1536 wgs
    int swz = (flat & 7) * 192 + (flat >> 3);
    const int q0 = (swz & 15) * 64;
    const int bh = swz >> 4;

    const int tid = threadIdx.x, lane = tid & 63, w = tid >> 6;
    const int p = lane & 15, g = lane >> 4;
    const short* qp = qb + (size_t)bh * NN * HD;
    const short* kp = kb + (size_t)bh * NN * HD;
    const short* vp = vtb + (size_t)bh * NN * HD;

    // stage Q (frag-major, same decomposition as K with w in place of jf)
    {
        const int kc = ((tid >> 4) & 3) * 8 + ((tid >> 6) & 1) * 32;
        const int r0 = tid >> 7;
        gload16(qp + (size_t)(q0 + r0 * 16 + p) * HD + kc, QP + tid * 8);
        gload16(qp + (size_t)(q0 + (r0 + 2) * 16 + p) * HD + kc,
                QP + (tid + 256) * 8);
    }
    stage_kv(kp, vp, 0, Kb[0], Vb[0], tid);
    wait_vm0_barrier();  // Q + KV tile 0 ready

    bf16x8 bQ[2];
    bQ[0] = *(const bf16x8*)(QP + (w * 2 + 0) * 512 + lane * 8);
    bQ[1] = *(const bf16x8*)(QP + (w * 2 + 1) * 512 + lane * 8);

    float m_run = -1e30f, l_run = 0.f;
    f32x4 oacc[4];
    const f32x4 z4 = {0.f, 0.f, 0.f, 0.f};
    #pragma unroll
    for (int df = 0; df < 4; ++df) oacc[df] = z4;
    short* Pw = QP + w * 1024;  // reuse Q region as this wave's P tile

    for (int t = 0; t < NT; ++t) {
        if (t) wait_vm0_barrier();  // tile t ready; buf (t+1)&1 free
        if (t < NT - 1)
            stage_kv(kp, vp, (t + 1) * 64, Kb[(t + 1) & 1], Vb[(t + 1) & 1], tid);
        const short* Kc = Kb[t & 1];
        const short* Vc = Vb[t & 1];

        // S^T = K * Q^T : lane holds S[q=p][j = jf*16 + 4g + r] (scaled)
        f32x4 sacc[4];
        #pragma unroll
        for (int jf = 0; jf < 4; ++jf) sacc[jf] = z4;
        #pragma unroll
        for (int ks = 0; ks < 2; ++ks) {
            #pragma unroll
            for (int jf = 0; jf < 4; ++jf) {
                bf16x8 aK =
                    *(const bf16x8*)(Kc + jf * 1024 + ks * 512 + lane * 8);
                sacc[jf] = __builtin_amdgcn_mfma_f32_16x16x32_bf16(
                    aK, bQ[ks], sacc[jf], 0, 0, 0);
            }
        }

        // online softmax, deferred rescale: keep m_run unless max grew by >3
        float tmax = sacc[0][0];
        #pragma unroll
        for (int jf = 0; jf < 4; ++jf)
            #pragma unroll
            for (int r = 0; r < 4; ++r) tmax = fmaxf(tmax, sacc[jf][r]);
        tmax = fmaxf(tmax, __shfl_xor(tmax, 16));
        tmax = fmaxf(tmax, __shfl_xor(tmax, 32));
        if (__any(tmax > m_run + 3.0f)) {
            const float mnew = fmaxf(m_run, tmax);
            const float fac = fast_exp2(m_run - mnew);
            m_run = mnew;
            l_run *= fac;
            #pragma unroll
            for (int r = 0; r < 4; ++r) {
                float fr = __shfl(fac, 4 * g + r, 16);
                #pragma unroll
                for (int df = 0; df < 4; ++df) oacc[df][r] *= fr;
            }
        }
        float lsum = 0.f;
        #pragma unroll
        for (int jf = 0; jf < 4; ++jf) {
            #pragma unroll
            for (int r = 0; r < 4; ++r) {
                float e = fast_exp2(sacc[jf][r] - m_run);
                sacc[jf][r] = e;  // keep for packing
                lsum += e;
            }
        }
        lsum += __shfl_xor(lsum, 16);
        lsum += __shfl_xor(lsum, 32);
        l_run += lsum;

        // P -> frag-major per-wave LDS tile (packed pairs, 2 insts / 4 elems)
        #pragma unroll
        for (int jf = 0; jf < 4; ++jf) {
            uint2 wpk;
            wpk.x = cvt_pk_bf16(sacc[jf][0], sacc[jf][1]);
            wpk.y = cvt_pk_bf16(sacc[jf][2], sacc[jf][3]);
            *(uint2*)(Pw + (jf >> 1) * 512 +
                      (((jf & 1) * 2 + (g >> 1)) * 16 + p) * 8 + (g & 1) * 4) =
                wpk;
        }
        asm volatile("s_waitcnt lgkmcnt(0)" ::: "memory");
        __builtin_amdgcn_sched_barrier(0);

        // PV: oacc += P * V (B-frags from V^T tile)
        #pragma unroll
        for (int ks = 0; ks < 2; ++ks) {
            bf16x8 aP = *(const bf16x8*)(Pw + ks * 512 + lane * 8);
            #pragma unroll
            for (int df = 0; df < 4; ++df) {
                bf16x8 bV =
                    *(const bf16x8*)(Vc + df * 1024 + ks * 512 + lane * 8);
                oacc[df] = __builtin_amdgcn_mfma_f32_16x16x32_bf16(
                    aP, bV, oacc[df], 0, 0, 0);
            }
        }
    }

    const float inv = 1.f / l_run;  // lane's q = p
    const int b = bh / HH, h = bh % HH;
    #pragma unroll
    for (int r = 0; r < 4; ++r) {
        float ir = __shfl(inv, 4 * g + r, 16);
        int n = q0 + w * 16 + 4 * g + r;
        #pragma unroll
        for (int df = 0; df < 4; ++df) {
            float v = oacc[df][r] * ir;
            unsigned short hi = f2bf(v);
            unsigned short lo = f2bf(v - bf2f(hi));
            size_t off = ((size_t)(b * NN + n)) * CC + h * HD + df * 16 + p;
            aoh[off] = (short)hi;
            aol[off] = (short)lo;
        }
    }
}

// ---------------------------------------------------------------------------
// gemm_proj (split-bf16, 3-MFMA): counted-wait ring-2 pipeline, 64KB LDS
// -> 2 blocks/CU. out = ao @ We_p + bp  (fp32 out)
// ---------------------------------------------------------------------------
__device__ __forceinline__ void stage_split(const short* __restrict__ gAh,
                                            const short* __restrict__ gAl,
                                            const short* __restrict__ gBh,
                                            const short* __restrict__ gBl,
                                            int rowA0, int rowB0, int kt,
                                            short* Lb, int tid) {
    const int fr = ((tid >> 6) << 4) | (tid & 15);
    const int kc = ((tid >> 4) & 3) * 8 + kt;
    const size_t ga0 = (size_t)(rowA0 + fr) * CC + kc;
    const size_t ga1 = ga0 + (size_t)64 * CC;
    const size_t gb0 = (size_t)(rowB0 + fr) * CC + kc;
    const size_t gb1 = gb0 + (size_t)64 * CC;
    short* d0 = Lb + tid * 8;
    short* d1 = Lb + (tid + 256) * 8;
    gload16(gAh + ga0, d0);
    gload16(gAh + ga1, d1);
    gload16(gAl + ga0, d0 + 4096);
    gload16(gAl + ga1, d1 + 4096);
    gload16(gBh + gb0, d0 + 8192);
    gload16(gBh + gb1, d1 + 8192);
    gload16(gBl + gb0, d0 + 12288);
    gload16(gBl + gb1, d1 + 12288);
}

__global__ __launch_bounds__(256, 2) void gemm_proj(
    const short* __restrict__ aoh, const short* __restrict__ aol,
    const short* __restrict__ wth, const short* __restrict__ wtl,
    const float* __restrict__ bp, float* __restrict__ out) {
    __shared__ __align__(16) short L[2][4 * 4096];  // 2 x 32 KiB

    int flat = blockIdx.x + 6 * blockIdx.y;  // 384 wgs
    int swz = (flat & 7) * 48 + (flat >> 3);
    int by = swz / 6, bx = swz - by * 6;
    const int m0 = by * 128, c0 = bx * 128;

    const short* wph = wth + (size_t)3 * WSZ;
    const short* wpl = wtl + (size_t)3 * WSZ;

    f32x4 acc[4][4];
    const f32x4 z4 = {0.f, 0.f, 0.f, 0.f};
    #pragma unroll
    for (int i = 0; i < 4; ++i)
        #pragma unroll
        for (int j = 0; j < 4; ++j) acc[i][j] = z4;

    const int tid = threadIdx.x, lane = tid & 63, w = tid >> 6;
    const int wm = w >> 1, wn = w & 1, p = lane & 15, g = lane >> 4;

    stage_split(aoh, aol, wph, wpl, m0, c0, 0, L[0], tid);
    for (int ki = 0; ki < 24; ++ki) {
        wait_vm0_barrier();  // tile ki ready; buf (ki-1)&1 free
        if (ki < 23)
            stage_split(aoh, aol, wph, wpl, m0, c0, (ki + 1) * 32,
                        L[(ki + 1) & 1], tid);  // overlaps this tile's MFMAs
        const short* Lb = L[ki & 1];
        const int fb = lane * 8;
        bf16x8 ah[4], al[4], bh[4], bl[4];
        #pragma unroll
        for (int i = 0; i < 4; ++i) {
            ah[i] = *(const bf16x8*)(Lb + (wm * 4 + i) * 512 + fb);
            al[i] = *(const bf16x8*)(Lb + 4096 + (wm * 4 + i) * 512 + fb);
        }
        #pragma unroll
        for (int j = 0; j < 4; ++j) {
            bh[j] = *(const bf16x8*)(Lb + 8192 + (wn * 4 + j) * 512 + fb);
            bl[j] = *(const bf16x8*)(Lb + 12288 + (wn * 4 + j) * 512 + fb);
        }
        #pragma unroll
        for (int i = 0; i < 4; ++i) {
            #pragma unroll
            for (int j = 0; j < 4; ++j) {
                acc[i][j] = __builtin_amdgcn_mfma_f32_16x16x32_bf16(
                    ah[i], bh[j], acc[i][j], 0, 0, 0);
                acc[i][j] = __builtin_amdgcn_mfma_f32_16x16x32_bf16(
                    ah[i], bl[j], acc[i][j], 0, 0, 0);
                acc[i][j] = __builtin_amdgcn_mfma_f32_16x16x32_bf16(
                    al[i], bh[j], acc[i][j], 0, 0, 0);
            }
        }
    }

    float bpv[4];
    #pragma unroll
    for (int j = 0; j < 4; ++j) bpv[j] = bp[c0 + wn * 64 + j * 16 + p];

    #pragma unroll
    for (int i = 0; i < 4; ++i) {
        #pragma unroll
        for (int r = 0; r < 4; ++r) {
            int m = m0 + wm * 64 + i * 16 + 4 * g + r;
            #pragma unroll
            for (int j = 0; j < 4; ++j) {
                int c = c0 + wn * 64 + j * 16 + p;
                out[(size_t)m * CC + c] = acc[i][j][r] + bpv[j];
            }
        }
    }
}

// ---------------------------------------------------------------------------
extern "C" void kernel_launch(void* const* d_in, const int* in_sizes, int n_in,
                              void* d_out, int out_size, void* d_ws,
                              size_t ws_size, hipStream_t stream) {
    const float* x = (const float*)d_in[0];
    const float* Wq = (const float*)d_in[1];
    const float* Wk = (const float*)d_in[2];
    const float* Wv = (const float*)d_in[3];
    const float* Wp = (const float*)d_in[4];
    const float* bp = (const float*)d_in[5];
    const float* la_q = (const float*)d_in[6];
    const float* lb_q = (const float*)d_in[7];
    const float* la_k = (const float*)d_in[8];
    const float* lb_k = (const float*)d_in[9];
    const float* la_v = (const float*)d_in[10];
    const float* lb_v = (const float*)d_in[11];
    const float* bw = (const float*)d_in[12];
    float* out = (float*)d_out;

    short* ws = (short*)d_ws;
    short* wt_hi = ws;                       // 4*WSZ
    short* wt_lo = wt_hi + (size_t)4 * WSZ;  // 4*WSZ
    short* x_hi = wt_lo + (size_t)4 * WSZ;   // MM*CC
    short* qbuf = x_hi + (size_t)MM * CC;    // [B,H,N,HD]
    short* kbuf = qbuf + (size_t)MM * CC;
    short* vtbuf = kbuf + (size_t)MM * CC;   // [B,H,HD,N]
    short* aoh = vtbuf + (size_t)MM * CC;    // [B,N,C] hi
    short* aol = aoh + (size_t)MM * CC;      // [B,N,C] lo

    prep_w<<<dim3(CC / 64, CC / 64, 4), 256, 0, stream>>>(
        Wq, Wk, Wv, Wp, la_q, lb_q, la_k, lb_k, la_v, lb_v, bw, wt_hi, wt_lo);
    prep_cvt<<<2048, 256, 0, stream>>>(x, x_hi, MM * CC / 4);
    gemm_qkv<<<dim3(CC / 128, MM / 128, 3), 256, 0, stream>>>(
        x_hi, wt_hi, qbuf, kbuf, vtbuf);
    attn<<<dim3(NN / 64, BB * HH), 256, 0, stream>>>(qbuf, kbuf, vtbuf, aoh, aol);
    gemm_proj<<<dim3(CC / 128, MM / 128), 256, 0, stream>>>(aoh, aol, wt_hi,
                                                            wt_lo, bp, out);
}

// Round 10
// 274.615 us; speedup vs baseline: 1.2708x; 1.2708x over previous
//
#include <hip/hip_runtime.h>

// Problem constants
#define BB 8
#define NN 1024
#define CC 768
#define HH 12
#define HD 64
#define RR 16
#define MM (BB * NN)   // 8192 tokens
#define WSZ (CC * CC)  // 589824 elements per weight matrix
#define NT (NN / 64)   // 16 kv tiles

// softmax scale folded with log2(e) for exp2f: HD^-0.5 * 1.4426950408889634
// (folded into the q-store of gemm_qkv; attn works in the scaled domain)
#define KSC 0.18033688011112042f

typedef short bf16x8 __attribute__((ext_vector_type(8)));
typedef short bf16x4 __attribute__((ext_vector_type(4)));
typedef float f32x4 __attribute__((ext_vector_type(4)));

__device__ __forceinline__ unsigned short f2bf(float f) {
    unsigned u = __builtin_bit_cast(unsigned, f);
    unsigned r = (u + 0x7FFFu + ((u >> 16) & 1u)) >> 16;
    return (unsigned short)r;
}
__device__ __forceinline__ float bf2f(unsigned short s) {
    return __builtin_bit_cast(float, ((unsigned)s) << 16);
}

// single-instruction exp2 (v_exp_f32); inputs here are finite, underflow->0 ok
__device__ __forceinline__ float fast_exp2(float x) {
#if __has_builtin(__builtin_amdgcn_exp2f)
    return __builtin_amdgcn_exp2f(x);
#else
    return exp2f(x);
#endif
}

// packed f32x2 -> bf16x2 (RNE, same as f2bf): dst[15:0]=a, dst[31:16]=b
__device__ __forceinline__ unsigned cvt_pk_bf16(float a, float b) {
    unsigned r;
    asm("v_cvt_pk_bf16_f32 %0, %1, %2" : "=v"(r) : "v"(a), "v"(b));
    return r;
}

// async 16B global -> LDS (DMA; LDS dest is wave-uniform base + lane*16)
__device__ __forceinline__ void gload16(const void* g, void* l) {
    __builtin_amdgcn_global_load_lds(
        (const __attribute__((address_space(1))) unsigned int*)g,
        (__attribute__((address_space(3))) unsigned int*)l, 16, 0, 0);
}

// counted-wait primitives (T4): never drain fresh loads inside the loop
__device__ __forceinline__ void wait_vm0_barrier() {
    asm volatile("s_waitcnt vmcnt(0)" ::: "memory");
    __builtin_amdgcn_s_barrier();
}

// ---------------------------------------------------------------------------
// prep_w: We_z = W_z + bw[z] * la_z @ lb_z  (z<3), We_3 = Wp.
// Output TRANSPOSED bf16 hi/lo: Wt[z][n][k]. (lo used only by proj's Wp.)
// ---------------------------------------------------------------------------
__global__ __launch_bounds__(256) void prep_w(
    const float* __restrict__ Wq, const float* __restrict__ Wk,
    const float* __restrict__ Wv, const float* __restrict__ Wp,
    const float* __restrict__ la_q, const float* __restrict__ lb_q,
    const float* __restrict__ la_k, const float* __restrict__ lb_k,
    const float* __restrict__ la_v, const float* __restrict__ lb_v,
    const float* __restrict__ bw, short* __restrict__ wt_hi,
    short* __restrict__ wt_lo) {
    __shared__ float laS[64][16];
    __shared__ float lbS[16][64];
    __shared__ float T[64][65];

    const int z = blockIdx.z;
    const int k0 = blockIdx.y * 64, n0 = blockIdx.x * 64;
    const int tid = threadIdx.x;

    const float* W = (z == 0) ? Wq : (z == 1) ? Wk : (z == 2) ? Wv : Wp;
    const float* la = (z == 0) ? la_q : (z == 1) ? la_k : la_v;
    const float* lb = (z == 0) ? lb_q : (z == 1) ? lb_k : lb_v;
    const float bwz = (z < 3) ? bw[z] : 0.f;

    if (z < 3) {
        #pragma unroll
        for (int e = 0; e < 4; ++e) {
            int idx = tid + 256 * e;
            laS[idx >> 4][idx & 15] = la[(size_t)(k0 + (idx >> 4)) * RR + (idx & 15)];
            lbS[idx >> 6][idx & 63] = lb[(size_t)(idx >> 6) * CC + n0 + (idx & 63)];
        }
    }
    __syncthreads();

    #pragma unroll
    for (int e = 0; e < 16; ++e) {
        int idx = tid + 256 * e;
        int row = idx >> 6, col = idx & 63;
        float v = W[(size_t)(k0 + row) * CC + n0 + col];
        if (z < 3) {
            float s = 0.f;
            #pragma unroll
            for (int r = 0; r < 16; ++r) s += laS[row][r] * lbS[r][col];
            v += bwz * s;
        }
        T[row][col] = v;
    }
    __syncthreads();

    short* oh = wt_hi + (size_t)z * WSZ;
    short* ol = wt_lo + (size_t)z * WSZ;
    #pragma unroll
    for (int e = 0; e < 16; ++e) {
        int idx = tid + 256 * e;
        int nrow = idx >> 6, kcol = idx & 63;
        float v = T[kcol][nrow];
        unsigned short hi = f2bf(v);
        unsigned short lo = f2bf(v - bf2f(hi));
        size_t off = (size_t)(n0 + nrow) * CC + k0 + kcol;
        oh[off] = (short)hi;
        ol[off] = (short)lo;
    }
}

// ---------------------------------------------------------------------------
// prep_cvt: fp32 -> bf16 (hi only; QKV GEMM runs plain bf16).
// ---------------------------------------------------------------------------
__global__ __launch_bounds__(256) void prep_cvt(const float* __restrict__ src,
                                                short* __restrict__ hi, int n4) {
    int i = blockIdx.x * 256 + threadIdx.x;
    const int stride = gridDim.x * 256;
    for (; i < n4; i += stride) {
        f32x4 v = ((const f32x4*)src)[i];
        bf16x4 h;
        #pragma unroll
        for (int c = 0; c < 4; ++c) h[c] = (short)f2bf(v[c]);
        ((bf16x4*)hi)[i] = h;
    }
}

// ---------------------------------------------------------------------------
// Plain bf16 MFMA GEMM core (QKV), counted-wait pipeline:
// per iter: vmcnt(0) [waits the stage issued ONE FULL iter ago] -> s_barrier
// -> issue stage(t+1) into the buffer freed by compute(t-1) -> compute t.
// LDS 2x16KB. Frag-major layout: element f (0..511) of each
// 128x32 sub-tile at f*16B, f=(row>>4)*64 + (kcol>>3)*16 + (row&15).
// ---------------------------------------------------------------------------
__device__ __forceinline__ void stage_plain(const short* __restrict__ gA,
                                            const short* __restrict__ gB,
                                            int rowA0, int rowB0, int kt,
                                            short* Lb, int tid) {
    const int fr = ((tid >> 6) << 4) | (tid & 15);  // row offset within tile
    const int kc = ((tid >> 4) & 3) * 8 + kt;       // col (shorts)
    const size_t ga0 = (size_t)(rowA0 + fr) * CC + kc;
    const size_t gb0 = (size_t)(rowB0 + fr) * CC + kc;
    short* d0 = Lb + tid * 8;
    short* d1 = Lb + (tid + 256) * 8;
    gload16(gA + ga0, d0);
    gload16(gA + ga0 + (size_t)64 * CC, d1);
    gload16(gB + gb0, d0 + 4096);
    gload16(gB + gb0 + (size_t)64 * CC, d1 + 4096);
}

__device__ __forceinline__ void gemm_core_plain(const short* __restrict__ gA,
                                                int rowA0,
                                                const short* __restrict__ gB,
                                                int rowB0, short (*L)[8192],
                                                f32x4 acc[4][4]) {
    const int tid = threadIdx.x, lane = tid & 63, w = tid >> 6;
    const int wm = w >> 1, wn = w & 1;
    stage_plain(gA, gB, rowA0, rowB0, 0, L[0], tid);
    for (int ki = 0; ki < 24; ++ki) {
        wait_vm0_barrier();  // tile ki ready for ALL waves; buf (ki-1)&1 free
        if (ki < 23)
            stage_plain(gA, gB, rowA0, rowB0, (ki + 1) * 32, L[(ki + 1) & 1],
                        tid);  // lands during compute of tile ki (full overlap)
        const short* Lb = L[ki & 1];
        bf16x8 ah[4], bh[4];
        #pragma unroll
        for (int i = 0; i < 4; ++i)
            ah[i] = *(const bf16x8*)(Lb + (wm * 4 + i) * 512 + lane * 8);
        #pragma unroll
        for (int j = 0; j < 4; ++j)
            bh[j] = *(const bf16x8*)(Lb + 4096 + (wn * 4 + j) * 512 + lane * 8);
        #pragma unroll
        for (int i = 0; i < 4; ++i)
            #pragma unroll
            for (int j = 0; j < 4; ++j)
                acc[i][j] = __builtin_amdgcn_mfma_f32_16x16x32_bf16(
                    ah[i], bh[j], acc[i][j], 0, 0, 0);
        // no end-of-iter barrier: next iter's vmcnt+barrier provides ordering
    }
}

// ---------------------------------------------------------------------------
// gemm_qkv (plain bf16): z=0/1 -> q/k bf16 [B,H,N,HD]; z=2 -> V^T [B,H,HD,N].
// q pre-scaled by KSC so attn needs no per-element scale multiply.
// NOTE: launch_bounds min-waves MUST stay at 4 — (256,5) caps VGPRs at ~96
// and spills the 64-reg accumulator to scratch (round 9: WRITE_SIZE 40->194MB,
// MfmaUtil 8%).
// ---------------------------------------------------------------------------
__global__ __launch_bounds__(256, 4) void gemm_qkv(
    const short* __restrict__ xh, const short* __restrict__ wth,
    short* __restrict__ qb, short* __restrict__ kb, short* __restrict__ vtb) {
    __shared__ __align__(16) short L[2][8192];  // 32 KiB

    // bijective XCD swizzle over the 1152-wg grid (1152 % 8 == 0)
    int flat = blockIdx.x + 6 * blockIdx.y + 384 * blockIdx.z;
    int swz = (flat & 7) * 144 + (flat >> 3);
    int z = swz / 384;
    int rem = swz - z * 384;
    int by = rem / 6, bx = rem - by * 6;
    const int m0 = by * 128, c0 = bx * 128;

    const short* wzh = wth + (size_t)z * WSZ;

    f32x4 acc[4][4];
    const f32x4 z4 = {0.f, 0.f, 0.f, 0.f};
    #pragma unroll
    for (int i = 0; i < 4; ++i)
        #pragma unroll
        for (int j = 0; j < 4; ++j) acc[i][j] = z4;

    const int lane = threadIdx.x & 63, w = threadIdx.x >> 6;
    const int wm = w >> 1, wn = w & 1, p = lane & 15, g = lane >> 4;

    if (z < 2) {
        gemm_core_plain(xh, m0, wzh, c0, L, acc);
        short* dst = (z == 0) ? qb : kb;
        const float scl = (z == 0) ? KSC : 1.0f;  // fold softmax scale into q
        #pragma unroll
        for (int i = 0; i < 4; ++i) {
            #pragma unroll
            for (int r = 0; r < 4; ++r) {
                int m = m0 + wm * 64 + i * 16 + 4 * g + r;
                int b = m >> 10, n = m & 1023;
                #pragma unroll
                for (int j = 0; j < 4; ++j) {
                    int c = c0 + wn * 64 + j * 16 + p;
                    int h = c >> 6, d = c & 63;
                    dst[(((size_t)(b * HH + h)) * NN + n) * HD + d] =
                        (short)f2bf(acc[i][j][r] * scl);
                }
            }
        }
    } else {
        gemm_core_plain(wzh, c0, xh, m0, L, acc);
        #pragma unroll
        for (int i = 0; i < 4; ++i) {
            #pragma unroll
            for (int r = 0; r < 4; ++r) {
                int c = c0 + wm * 64 + i * 16 + 4 * g + r;
                int h = c >> 6, d = c & 63;
                #pragma unroll
                for (int j = 0; j < 4; ++j) {
                    int m = m0 + wn * 64 + j * 16 + p;
                    int b = m >> 10, n = m & 1023;
                    vtb[(((size_t)(b * HH + h)) * HD + d) * NN + n] =
                        (short)f2bf(acc[i][j][r]);
                }
            }
        }
    }
}

// ---------------------------------------------------------------------------
// attn: bf16 MFMA flash attention, counted-wait single-barrier loop.
// Per iter: vmcnt(0)+barrier (tile t ready) -> stage(t+1) -> QK/softmax/PV.
// Q tile LDS reused as per-wave P tile. 40KB LDS -> 4 blocks/CU.
// ---------------------------------------------------------------------------
__device__ __forceinline__ void stage_kv(const short* __restrict__ kp,
                                         const short* __restrict__ vp, int j0,
                                         short* Kd, short* Vd, int tid) {
    const int pp = tid & 15;
    const int kc = ((tid >> 4) & 3) * 8 + ((tid >> 6) & 1) * 32;
    const int r0 = tid >> 7;  // 0..1; second element uses r0+2
    gload16(kp + (size_t)(j0 + r0 * 16 + pp) * HD + kc, Kd + tid * 8);
    gload16(kp + (size_t)(j0 + (r0 + 2) * 16 + pp) * HD + kc, Kd + (tid + 256) * 8);
    gload16(vp + (size_t)(r0 * 16 + pp) * NN + j0 + kc, Vd + tid * 8);
    gload16(vp + (size_t)((r0 + 2) * 16 + pp) * NN + j0 + kc, Vd + (tid + 256) * 8);
}

__global__ __launch_bounds__(256, 4) void attn(const short* __restrict__ qb,
                                               const short* __restrict__ kb,
                                               const short* __restrict__ vtb,
                                               short* __restrict__ aoh,
                                               short* __restrict__ aol) {
    __shared__ __align__(16) short QP[4096];   // Q tile, then P tiles
    __shared__ __align__(16) short Kb[2][4096];
    __shared__ __align__(16) short Vb[2][4096];

    // XCD swizzle: 12 consecutive (b,h) per XCD -> KV L2-resident
    int flat = blockIdx.x + 16 * blockIdx.y;  // 1536 wgs
    int swz = (flat & 7) * 192 + (flat >> 3);
    const int q0 = (swz & 15) * 64;
    const int bh = swz >> 4;

    const int tid = threadIdx.x, lane = tid & 63, w = tid >> 6;
    const int p = lane & 15, g = lane >> 4;
    const short* qp = qb + (size_t)bh * NN * HD;
    const short* kp = kb + (size_t)bh * NN * HD;
    const short* vp = vtb + (size_t)bh * NN * HD;

    // stage Q (frag-major, same decomposition as K with w in place of jf)
    {
        const int kc = ((tid >> 4) & 3) * 8 + ((tid >> 6) & 1) * 32;
        const int r0 = tid >> 7;
        gload16(qp + (size_t)(q0 + r0 * 16 + p) * HD + kc, QP + tid * 8);
        gload16(qp + (size_t)(q0 + (r0 + 2) * 16 + p) * HD + kc,
                QP + (tid + 256) * 8);
    }
    stage_kv(kp, vp, 0, Kb[0], Vb[0], tid);
    wait_vm0_barrier();  // Q + KV tile 0 ready

    bf16x8 bQ[2];
    bQ[0] = *(const bf16x8*)(QP + (w * 2 + 0) * 512 + lane * 8);
    bQ[1] = *(const bf16x8*)(QP + (w * 2 + 1) * 512 + lane * 8);

    float m_run = -1e30f, l_run = 0.f;
    f32x4 oacc[4];
    const f32x4 z4 = {0.f, 0.f, 0.f, 0.f};
    #pragma unroll
    for (int df = 0; df < 4; ++df) oacc[df] = z4;
    short* Pw = QP + w * 1024;  // reuse Q region as this wave's P tile

    for (int t = 0; t < NT; ++t) {
        if (t) wait_vm0_barrier();  // tile t ready; buf (t+1)&1 free
        if (t < NT - 1)
            stage_kv(kp, vp, (t + 1) * 64, Kb[(t + 1) & 1], Vb[(t + 1) & 1], tid);
        const short* Kc = Kb[t & 1];
        const short* Vc = Vb[t & 1];

        // S^T = K * Q^T : lane holds S[q=p][j = jf*16 + 4g + r] (scaled)
        f32x4 sacc[4];
        #pragma unroll
        for (int jf = 0; jf < 4; ++jf) sacc[jf] = z4;
        #pragma unroll
        for (int ks = 0; ks < 2; ++ks) {
            #pragma unroll
            for (int jf = 0; jf < 4; ++jf) {
                bf16x8 aK =
                    *(const bf16x8*)(Kc + jf * 1024 + ks * 512 + lane * 8);
                sacc[jf] = __builtin_amdgcn_mfma_f32_16x16x32_bf16(
                    aK, bQ[ks], sacc[jf], 0, 0, 0);
            }
        }

        // online softmax, deferred rescale: keep m_run unless max grew by >3
        float tmax = sacc[0][0];
        #pragma unroll
        for (int jf = 0; jf < 4; ++jf)
            #pragma unroll
            for (int r = 0; r < 4; ++r) tmax = fmaxf(tmax, sacc[jf][r]);
        tmax = fmaxf(tmax, __shfl_xor(tmax, 16));
        tmax = fmaxf(tmax, __shfl_xor(tmax, 32));
        if (__any(tmax > m_run + 3.0f)) {
            const float mnew = fmaxf(m_run, tmax);
            const float fac = fast_exp2(m_run - mnew);
            m_run = mnew;
            l_run *= fac;
            #pragma unroll
            for (int r = 0; r < 4; ++r) {
                float fr = __shfl(fac, 4 * g + r, 16);
                #pragma unroll
                for (int df = 0; df < 4; ++df) oacc[df][r] *= fr;
            }
        }
        float lsum = 0.f;
        #pragma unroll
        for (int jf = 0; jf < 4; ++jf) {
            #pragma unroll
            for (int r = 0; r < 4; ++r) {
                float e = fast_exp2(sacc[jf][r] - m_run);
                sacc[jf][r] = e;  // keep for packing
                lsum += e;
            }
        }
        lsum += __shfl_xor(lsum, 16);
        lsum += __shfl_xor(lsum, 32);
        l_run += lsum;

        // P -> frag-major per-wave LDS tile (packed pairs, 2 insts / 4 elems)
        #pragma unroll
        for (int jf = 0; jf < 4; ++jf) {
            uint2 wpk;
            wpk.x = cvt_pk_bf16(sacc[jf][0], sacc[jf][1]);
            wpk.y = cvt_pk_bf16(sacc[jf][2], sacc[jf][3]);
            *(uint2*)(Pw + (jf >> 1) * 512 +
                      (((jf & 1) * 2 + (g >> 1)) * 16 + p) * 8 + (g & 1) * 4) =
                wpk;
        }
        asm volatile("s_waitcnt lgkmcnt(0)" ::: "memory");
        __builtin_amdgcn_sched_barrier(0);

        // PV: oacc += P * V (B-frags from V^T tile)
        #pragma unroll
        for (int ks = 0; ks < 2; ++ks) {
            bf16x8 aP = *(const bf16x8*)(Pw + ks * 512 + lane * 8);
            #pragma unroll
            for (int df = 0; df < 4; ++df) {
                bf16x8 bV =
                    *(const bf16x8*)(Vc + df * 1024 + ks * 512 + lane * 8);
                oacc[df] = __builtin_amdgcn_mfma_f32_16x16x32_bf16(
                    aP, bV, oacc[df], 0, 0, 0);
            }
        }
    }

    const float inv = 1.f / l_run;  // lane's q = p
    const int b = bh / HH, h = bh % HH;
    #pragma unroll
    for (int r = 0; r < 4; ++r) {
        float ir = __shfl(inv, 4 * g + r, 16);
        int n = q0 + w * 16 + 4 * g + r;
        #pragma unroll
        for (int df = 0; df < 4; ++df) {
            float v = oacc[df][r] * ir;
            unsigned short hi = f2bf(v);
            unsigned short lo = f2bf(v - bf2f(hi));
            size_t off = ((size_t)(b * NN + n)) * CC + h * HD + df * 16 + p;
            aoh[off] = (short)hi;
            aol[off] = (short)lo;
        }
    }
}

// ---------------------------------------------------------------------------
// gemm_proj (split-bf16, 3-MFMA): counted-wait ring-2 pipeline, 64KB LDS
// -> 2 blocks/CU. out = ao @ We_p + bp  (fp32 out)
// ---------------------------------------------------------------------------
__device__ __forceinline__ void stage_split(const short* __restrict__ gAh,
                                            const short* __restrict__ gAl,
                                            const short* __restrict__ gBh,
                                            const short* __restrict__ gBl,
                                            int rowA0, int rowB0, int kt,
                                            short* Lb, int tid) {
    const int fr = ((tid >> 6) << 4) | (tid & 15);
    const int kc = ((tid >> 4) & 3) * 8 + kt;
    const size_t ga0 = (size_t)(rowA0 + fr) * CC + kc;
    const size_t ga1 = ga0 + (size_t)64 * CC;
    const size_t gb0 = (size_t)(rowB0 + fr) * CC + kc;
    const size_t gb1 = gb0 + (size_t)64 * CC;
    short* d0 = Lb + tid * 8;
    short* d1 = Lb + (tid + 256) * 8;
    gload16(gAh + ga0, d0);
    gload16(gAh + ga1, d1);
    gload16(gAl + ga0, d0 + 4096);
    gload16(gAl + ga1, d1 + 4096);
    gload16(gBh + gb0, d0 + 8192);
    gload16(gBh + gb1, d1 + 8192);
    gload16(gBl + gb0, d0 + 12288);
    gload16(gBl + gb1, d1 + 12288);
}

__global__ __launch_bounds__(256, 2) void gemm_proj(
    const short* __restrict__ aoh, const short* __restrict__ aol,
    const short* __restrict__ wth, const short* __restrict__ wtl,
    const float* __restrict__ bp, float* __restrict__ out) {
    __shared__ __align__(16) short L[2][4 * 4096];  // 2 x 32 KiB

    int flat = blockIdx.x + 6 * blockIdx.y;  // 384 wgs
    int swz = (flat & 7) * 48 + (flat >> 3);
    int by = swz / 6, bx = swz - by * 6;
    const int m0 = by * 128, c0 = bx * 128;

    const short* wph = wth + (size_t)3 * WSZ;
    const short* wpl = wtl + (size_t)3 * WSZ;

    f32x4 acc[4][4];
    const f32x4 z4 = {0.f, 0.f, 0.f, 0.f};
    #pragma unroll
    for (int i = 0; i < 4; ++i)
        #pragma unroll
        for (int j = 0; j < 4; ++j) acc[i][j] = z4;

    const int tid = threadIdx.x, lane = tid & 63, w = tid >> 6;
    const int wm = w >> 1, wn = w & 1, p = lane & 15, g = lane >> 4;

    stage_split(aoh, aol, wph, wpl, m0, c0, 0, L[0], tid);
    for (int ki = 0; ki < 24; ++ki) {
        wait_vm0_barrier();  // tile ki ready; buf (ki-1)&1 free
        if (ki < 23)
            stage_split(aoh, aol, wph, wpl, m0, c0, (ki + 1) * 32,
                        L[(ki + 1) & 1], tid);  // overlaps this tile's MFMAs
        const short* Lb = L[ki & 1];
        const int fb = lane * 8;
        bf16x8 ah[4], al[4], bh[4], bl[4];
        #pragma unroll
        for (int i = 0; i < 4; ++i) {
            ah[i] = *(const bf16x8*)(Lb + (wm * 4 + i) * 512 + fb);
            al[i] = *(const bf16x8*)(Lb + 4096 + (wm * 4 + i) * 512 + fb);
        }
        #pragma unroll
        for (int j = 0; j < 4; ++j) {
            bh[j] = *(const bf16x8*)(Lb + 8192 + (wn * 4 + j) * 512 + fb);
            bl[j] = *(const bf16x8*)(Lb + 12288 + (wn * 4 + j) * 512 + fb);
        }
        #pragma unroll
        for (int i = 0; i < 4; ++i) {
            #pragma unroll
            for (int j = 0; j < 4; ++j) {
                acc[i][j] = __builtin_amdgcn_mfma_f32_16x16x32_bf16(
                    ah[i], bh[j], acc[i][j], 0, 0, 0);
                acc[i][j] = __builtin_amdgcn_mfma_f32_16x16x32_bf16(
                    ah[i], bl[j], acc[i][j], 0, 0, 0);
                acc[i][j] = __builtin_amdgcn_mfma_f32_16x16x32_bf16(
                    al[i], bh[j], acc[i][j], 0, 0, 0);
            }
        }
    }

    float bpv[4];
    #pragma unroll
    for (int j = 0; j < 4; ++j) bpv[j] = bp[c0 + wn * 64 + j * 16 + p];

    #pragma unroll
    for (int i = 0; i < 4; ++i) {
        #pragma unroll
        for (int r = 0; r < 4; ++r) {
            int m = m0 + wm * 64 + i * 16 + 4 * g + r;
            #pragma unroll
            for (int j = 0; j < 4; ++j) {
                int c = c0 + wn * 64 + j * 16 + p;
                out[(size_t)m * CC + c] = acc[i][j][r] + bpv[j];
            }
        }
    }
}

// ---------------------------------------------------------------------------
extern "C" void kernel_launch(void* const* d_in, const int* in_sizes, int n_in,
                              void* d_out, int out_size, void* d_ws,
                              size_t ws_size, hipStream_t stream) {
    const float* x = (const float*)d_in[0];
    const float* Wq = (const float*)d_in[1];
    const float* Wk = (const float*)d_in[2];
    const float* Wv = (const float*)d_in[3];
    const float* Wp = (const float*)d_in[4];
    const float* bp = (const float*)d_in[5];
    const float* la_q = (const float*)d_in[6];
    const float* lb_q = (const float*)d_in[7];
    const float* la_k = (const float*)d_in[8];
    const float* lb_k = (const float*)d_in[9];
    const float* la_v = (const float*)d_in[10];
    const float* lb_v = (const float*)d_in[11];
    const float* bw = (const float*)d_in[12];
    float* out = (float*)d_out;

    short* ws = (short*)d_ws;
    short* wt_hi = ws;                       // 4*WSZ
    short* wt_lo = wt_hi + (size_t)4 * WSZ;  // 4*WSZ
    short* x_hi = wt_lo + (size_t)4 * WSZ;   // MM*CC
    short* qbuf = x_hi + (size_t)MM * CC;    // [B,H,N,HD]
    short* kbuf = qbuf + (size_t)MM * CC;
    short* vtbuf = kbuf + (size_t)MM * CC;   // [B,H,HD,N]
    short* aoh = vtbuf + (size_t)MM * CC;    // [B,N,C] hi
    short* aol = aoh + (size_t)MM * CC;      // [B,N,C] lo

    prep_w<<<dim3(CC / 64, CC / 64, 4), 256, 0, stream>>>(
        Wq, Wk, Wv, Wp, la_q, lb_q, la_k, lb_k, la_v, lb_v, bw, wt_hi, wt_lo);
    prep_cvt<<<2048, 256, 0, stream>>>(x, x_hi, MM * CC / 4);
    gemm_qkv<<<dim3(CC / 128, MM / 128, 3), 256, 0, stream>>>(
        x_hi, wt_hi, qbuf, kbuf, vtbuf);
    attn<<<dim3(NN / 64, BB * HH), 256, 0, stream>>>(qbuf, kbuf, vtbuf, aoh, aol);
    gemm_proj<<<dim3(CC / 128, MM / 128), 256, 0, stream>>>(aoh, aol, wt_hi,
                                                            wt_lo, bp, out);
}

// Round 11
// 266.784 us; speedup vs baseline: 1.3081x; 1.0293x over previous
//
#include <hip/hip_runtime.h>

// Problem constants
#define BB 8
#define NN 1024
#define CC 768
#define HH 12
#define HD 64
#define RR 16
#define MM (BB * NN)   // 8192 tokens
#define WSZ (CC * CC)  // 589824 elements per weight matrix
#define NT (NN / 64)   // 16 kv tiles

// softmax scale folded with log2(e) for exp2f: HD^-0.5 * 1.4426950408889634
// (folded into the q-store of gemm_qkv; attn works in the scaled domain)
#define KSC 0.18033688011112042f

typedef short bf16x8 __attribute__((ext_vector_type(8)));
typedef short bf16x4 __attribute__((ext_vector_type(4)));
typedef float f32x4 __attribute__((ext_vector_type(4)));

__device__ __forceinline__ unsigned short f2bf(float f) {
    unsigned u = __builtin_bit_cast(unsigned, f);
    unsigned r = (u + 0x7FFFu + ((u >> 16) & 1u)) >> 16;
    return (unsigned short)r;
}
__device__ __forceinline__ float bf2f(unsigned short s) {
    return __builtin_bit_cast(float, ((unsigned)s) << 16);
}

// single-instruction exp2 (v_exp_f32); inputs here are finite, underflow->0 ok
__device__ __forceinline__ float fast_exp2(float x) {
#if __has_builtin(__builtin_amdgcn_exp2f)
    return __builtin_amdgcn_exp2f(x);
#else
    return exp2f(x);
#endif
}

// packed f32x2 -> bf16x2 (RNE, same as f2bf): dst[15:0]=a, dst[31:16]=b
__device__ __forceinline__ unsigned cvt_pk_bf16(float a, float b) {
    unsigned r;
    asm("v_cvt_pk_bf16_f32 %0, %1, %2" : "=v"(r) : "v"(a), "v"(b));
    return r;
}

// async 16B global -> LDS (DMA; LDS dest is wave-uniform base + lane*16)
__device__ __forceinline__ void gload16(const void* g, void* l) {
    __builtin_amdgcn_global_load_lds(
        (const __attribute__((address_space(1))) unsigned int*)g,
        (__attribute__((address_space(3))) unsigned int*)l, 16, 0, 0);
}

// counted-wait primitives (T4): never drain fresh loads inside the loop
__device__ __forceinline__ void wait_vm0_barrier() {
    asm volatile("s_waitcnt vmcnt(0)" ::: "memory");
    __builtin_amdgcn_s_barrier();
}

// ---------------------------------------------------------------------------
// prep_w: We_z = W_z + bw[z] * la_z @ lb_z  (z<3), We_3 = Wp.
// Output TRANSPOSED bf16 hi/lo: Wt[z][n][k]. (lo used only by proj's Wp.)
// ---------------------------------------------------------------------------
__global__ __launch_bounds__(256) void prep_w(
    const float* __restrict__ Wq, const float* __restrict__ Wk,
    const float* __restrict__ Wv, const float* __restrict__ Wp,
    const float* __restrict__ la_q, const float* __restrict__ lb_q,
    const float* __restrict__ la_k, const float* __restrict__ lb_k,
    const float* __restrict__ la_v, const float* __restrict__ lb_v,
    const float* __restrict__ bw, short* __restrict__ wt_hi,
    short* __restrict__ wt_lo) {
    __shared__ float laS[64][16];
    __shared__ float lbS[16][64];
    __shared__ float T[64][65];

    const int z = blockIdx.z;
    const int k0 = blockIdx.y * 64, n0 = blockIdx.x * 64;
    const int tid = threadIdx.x;

    const float* W = (z == 0) ? Wq : (z == 1) ? Wk : (z == 2) ? Wv : Wp;
    const float* la = (z == 0) ? la_q : (z == 1) ? la_k : la_v;
    const float* lb = (z == 0) ? lb_q : (z == 1) ? lb_k : lb_v;
    const float bwz = (z < 3) ? bw[z] : 0.f;

    if (z < 3) {
        #pragma unroll
        for (int e = 0; e < 4; ++e) {
            int idx = tid + 256 * e;
            laS[idx >> 4][idx & 15] = la[(size_t)(k0 + (idx >> 4)) * RR + (idx & 15)];
            lbS[idx >> 6][idx & 63] = lb[(size_t)(idx >> 6) * CC + n0 + (idx & 63)];
        }
    }
    __syncthreads();

    #pragma unroll
    for (int e = 0; e < 16; ++e) {
        int idx = tid + 256 * e;
        int row = idx >> 6, col = idx & 63;
        float v = W[(size_t)(k0 + row) * CC + n0 + col];
        if (z < 3) {
            float s = 0.f;
            #pragma unroll
            for (int r = 0; r < 16; ++r) s += laS[row][r] * lbS[r][col];
            v += bwz * s;
        }
        T[row][col] = v;
    }
    __syncthreads();

    short* oh = wt_hi + (size_t)z * WSZ;
    short* ol = wt_lo + (size_t)z * WSZ;
    #pragma unroll
    for (int e = 0; e < 16; ++e) {
        int idx = tid + 256 * e;
        int nrow = idx >> 6, kcol = idx & 63;
        float v = T[kcol][nrow];
        unsigned short hi = f2bf(v);
        unsigned short lo = f2bf(v - bf2f(hi));
        size_t off = (size_t)(n0 + nrow) * CC + k0 + kcol;
        oh[off] = (short)hi;
        ol[off] = (short)lo;
    }
}

// ---------------------------------------------------------------------------
// prep_cvt: fp32 -> bf16 (hi only; QKV GEMM runs plain bf16).
// ---------------------------------------------------------------------------
__global__ __launch_bounds__(256) void prep_cvt(const float* __restrict__ src,
                                                short* __restrict__ hi, int n4) {
    int i = blockIdx.x * 256 + threadIdx.x;
    const int stride = gridDim.x * 256;
    for (; i < n4; i += stride) {
        f32x4 v = ((const f32x4*)src)[i];
        bf16x4 h;
        #pragma unroll
        for (int c = 0; c < 4; ++c) h[c] = (short)f2bf(v[c]);
        ((bf16x4*)hi)[i] = h;
    }
}

// ---------------------------------------------------------------------------
// gemm_qkv_fused (plain bf16): ONE kernel computes q, k, v for its 128x128
// tile. A (= x rows) is staged ONCE per K-step and reused by all three
// weight tiles: 48 MFMA/wave per barrier (3x the old per-barrier compute,
// 1/3 the A staging + barrier crossings per FLOP).
// LDS ring-2 x 32KB: per buffer (shorts): A[0,4096) B0[4096,8192)
// B1[8192,12288) B2[12288,16384). Frag-major layout as before.
// Counted-wait pipeline per iter: vmcnt(0)+barrier -> stage(t+1) -> compute.
// q,k stored [B,H,N,HD] (q pre-scaled by KSC); v transposed via padded-LDS
// roundtrip (epilogue-only) and stored [B,H,HD,N].
// launch_bounds(256,2): acc[3][4][4]=192 VGPR needs the 256-reg budget.
// ---------------------------------------------------------------------------
__device__ __forceinline__ void stage_fused(const short* __restrict__ xh,
                                            const short* __restrict__ wth,
                                            int m0, int c0, int kt, short* Lb,
                                            int tid) {
    const int fr = ((tid >> 6) << 4) | (tid & 15);  // row offset within tile
    const int kc = ((tid >> 4) & 3) * 8 + kt;       // col (shorts)
    const size_t ga = (size_t)(m0 + fr) * CC + kc;   // x rows
    const size_t gw = (size_t)(c0 + fr) * CC + kc;   // wt rows (= out cols)
    short* d0 = Lb + tid * 8;
    short* d1 = Lb + (tid + 256) * 8;
    gload16(xh + ga, d0);
    gload16(xh + ga + (size_t)64 * CC, d1);
    gload16(wth + gw, d0 + 4096);
    gload16(wth + gw + (size_t)64 * CC, d1 + 4096);
    gload16(wth + WSZ + gw, d0 + 8192);
    gload16(wth + WSZ + gw + (size_t)64 * CC, d1 + 8192);
    gload16(wth + 2 * (size_t)WSZ + gw, d0 + 12288);
    gload16(wth + 2 * (size_t)WSZ + gw + (size_t)64 * CC, d1 + 12288);
}

__global__ __launch_bounds__(256, 2) void gemm_qkv_fused(
    const short* __restrict__ xh, const short* __restrict__ wth,
    short* __restrict__ qb, short* __restrict__ kb, short* __restrict__ vtb) {
    __shared__ __align__(16) short L[2][16384];  // 64 KiB -> 2 blocks/CU

    // bijective XCD swizzle over the 384-wg grid (384 % 8 == 0)
    int flat = blockIdx.x + 6 * blockIdx.y;
    int swz = (flat & 7) * 48 + (flat >> 3);
    int by = swz / 6, bx = swz - by * 6;
    const int m0 = by * 128, c0 = bx * 128;

    const int tid = threadIdx.x, lane = tid & 63, w = tid >> 6;
    const int wm = w >> 1, wn = w & 1, p = lane & 15, g = lane >> 4;

    f32x4 acc[3][4][4];
    const f32x4 z4 = {0.f, 0.f, 0.f, 0.f};
    #pragma unroll
    for (int z = 0; z < 3; ++z)
        #pragma unroll
        for (int i = 0; i < 4; ++i)
            #pragma unroll
            for (int j = 0; j < 4; ++j) acc[z][i][j] = z4;

    stage_fused(xh, wth, m0, c0, 0, L[0], tid);
    for (int ki = 0; ki < 24; ++ki) {
        wait_vm0_barrier();  // tile ki ready for ALL waves; buf (ki-1)&1 free
        if (ki < 23)
            stage_fused(xh, wth, m0, c0, (ki + 1) * 32, L[(ki + 1) & 1],
                        tid);  // lands under this tile's 48 MFMAs
        const short* Lb = L[ki & 1];
        bf16x8 ah[4];
        #pragma unroll
        for (int i = 0; i < 4; ++i)
            ah[i] = *(const bf16x8*)(Lb + (wm * 4 + i) * 512 + lane * 8);
        #pragma unroll
        for (int z = 0; z < 3; ++z) {
            const short* Bz = Lb + 4096 * (z + 1);
            bf16x8 bh[4];
            #pragma unroll
            for (int j = 0; j < 4; ++j)
                bh[j] = *(const bf16x8*)(Bz + (wn * 4 + j) * 512 + lane * 8);
            #pragma unroll
            for (int i = 0; i < 4; ++i)
                #pragma unroll
                for (int j = 0; j < 4; ++j)
                    acc[z][i][j] = __builtin_amdgcn_mfma_f32_16x16x32_bf16(
                        ah[i], bh[j], acc[z][i][j], 0, 0, 0);
        }
        // no end-of-iter barrier: next iter's vmcnt+barrier orders buf reuse
    }

    // q (scaled) and k: direct [B,H,N,HD] stores
    #pragma unroll
    for (int zz = 0; zz < 2; ++zz) {
        short* dst = (zz == 0) ? qb : kb;
        const float scl = (zz == 0) ? KSC : 1.0f;
        #pragma unroll
        for (int i = 0; i < 4; ++i) {
            #pragma unroll
            for (int r = 0; r < 4; ++r) {
                int m = m0 + wm * 64 + i * 16 + 4 * g + r;
                int b = m >> 10, n = m & 1023;
                #pragma unroll
                for (int j = 0; j < 4; ++j) {
                    int c = c0 + wn * 64 + j * 16 + p;
                    int h = c >> 6, d = c & 63;
                    dst[(((size_t)(b * HH + h)) * NN + n) * HD + d] =
                        (short)f2bf(acc[zz][i][j][r] * scl);
                }
            }
        }
    }

    // v: transpose via padded LDS (stride 132 shorts -> 2-way banks max),
    // then coalesced [B,H,HD,N] stores (128 shorts contiguous per thread).
    __syncthreads();  // all compute ds_reads done; L reusable as scratch
    short* Lt = &L[0][0];  // flat 32768 shorts; need 128*132 = 16896
    #pragma unroll
    for (int i = 0; i < 4; ++i) {
        #pragma unroll
        for (int r = 0; r < 4; ++r) {
            int mp = wm * 64 + i * 16 + 4 * g + r;
            #pragma unroll
            for (int j = 0; j < 4; ++j) {
                int cp = wn * 64 + j * 16 + p;
                Lt[cp * 132 + mp] = (short)f2bf(acc[2][i][j][r]);
            }
        }
    }
    __syncthreads();
    {
        const int cp = tid >> 1, mh = (tid & 1) * 64;
        const int c = c0 + cp, h = c >> 6, d = c & 63;
        const int b = m0 >> 10, nbase = m0 & 1023;
        short* dst =
            vtb + ((size_t)(b * HH + h) * HD + d) * NN + nbase + mh;
        #pragma unroll
        for (int e = 0; e < 16; ++e)
            *(bf16x4*)(dst + e * 4) =
                *(const bf16x4*)(Lt + cp * 132 + mh + e * 4);
    }
}

// ---------------------------------------------------------------------------
// attn: bf16 MFMA flash attention, counted-wait single-barrier loop.
// Per iter: vmcnt(0)+barrier (tile t ready) -> stage(t+1) -> QK/softmax/PV.
// Q tile LDS reused as per-wave P tile. 40KB LDS -> 4 blocks/CU.
// ---------------------------------------------------------------------------
__device__ __forceinline__ void stage_kv(const short* __restrict__ kp,
                                         const short* __restrict__ vp, int j0,
                                         short* Kd, short* Vd, int tid) {
    const int pp = tid & 15;
    const int kc = ((tid >> 4) & 3) * 8 + ((tid >> 6) & 1) * 32;
    const int r0 = tid >> 7;  // 0..1; second element uses r0+2
    gload16(kp + (size_t)(j0 + r0 * 16 + pp) * HD + kc, Kd + tid * 8);
    gload16(kp + (size_t)(j0 + (r0 + 2) * 16 + pp) * HD + kc, Kd + (tid + 256) * 8);
    gload16(vp + (size_t)(r0 * 16 + pp) * NN + j0 + kc, Vd + tid * 8);
    gload16(vp + (size_t)((r0 + 2) * 16 + pp) * NN + j0 + kc, Vd + (tid + 256) * 8);
}

__global__ __launch_bounds__(256, 4) void attn(const short* __restrict__ qb,
                                               const short* __restrict__ kb,
                                               const short* __restrict__ vtb,
                                               short* __restrict__ aoh,
                                               short* __restrict__ aol) {
    __shared__ __align__(16) short QP[4096];   // Q tile, then P tiles
    __shared__ __align__(16) short Kb[2][4096];
    __shared__ __align__(16) short Vb[2][4096];

    // XCD swizzle: 12 consecutive (b,h) per XCD -> KV L2-resident
    int flat = blockIdx.x + 16 * blockIdx.y;  // 1536 wgs
    int swz = (flat & 7) * 192 + (flat >> 3);
    const int q0 = (swz & 15) * 64;
    const int bh = swz >> 4;

    const int tid = threadIdx.x, lane = tid & 63, w = tid >> 6;
    const int p = lane & 15, g = lane >> 4;
    const short* qp = qb + (size_t)bh * NN * HD;
    const short* kp = kb + (size_t)bh * NN * HD;
    const short* vp = vtb + (size_t)bh * NN * HD;

    // stage Q (frag-major, same decomposition as K with w in place of jf)
    {
        const int kc = ((tid >> 4) & 3) * 8 + ((tid >> 6) & 1) * 32;
        const int r0 = tid >> 7;
        gload16(qp + (size_t)(q0 + r0 * 16 + p) * HD + kc, QP + tid * 8);
        gload16(qp + (size_t)(q0 + (r0 + 2) * 16 + p) * HD + kc,
                QP + (tid + 256) * 8);
    }
    stage_kv(kp, vp, 0, Kb[0], Vb[0], tid);
    wait_vm0_barrier();  // Q + KV tile 0 ready

    bf16x8 bQ[2];
    bQ[0] = *(const bf16x8*)(QP + (w * 2 + 0) * 512 + lane * 8);
    bQ[1] = *(const bf16x8*)(QP + (w * 2 + 1) * 512 + lane * 8);

    float m_run = -1e30f, l_run = 0.f;
    f32x4 oacc[4];
    const f32x4 z4 = {0.f, 0.f, 0.f, 0.f};
    #pragma unroll
    for (int df = 0; df < 4; ++df) oacc[df] = z4;
    short* Pw = QP + w * 1024;  // reuse Q region as this wave's P tile

    for (int t = 0; t < NT; ++t) {
        if (t) wait_vm0_barrier();  // tile t ready; buf (t+1)&1 free
        if (t < NT - 1)
            stage_kv(kp, vp, (t + 1) * 64, Kb[(t + 1) & 1], Vb[(t + 1) & 1], tid);
        const short* Kc = Kb[t & 1];
        const short* Vc = Vb[t & 1];

        // S^T = K * Q^T : lane holds S[q=p][j = jf*16 + 4g + r] (scaled)
        f32x4 sacc[4];
        #pragma unroll
        for (int jf = 0; jf < 4; ++jf) sacc[jf] = z4;
        #pragma unroll
        for (int ks = 0; ks < 2; ++ks) {
            #pragma unroll
            for (int jf = 0; jf < 4; ++jf) {
                bf16x8 aK =
                    *(const bf16x8*)(Kc + jf * 1024 + ks * 512 + lane * 8);
                sacc[jf] = __builtin_amdgcn_mfma_f32_16x16x32_bf16(
                    aK, bQ[ks], sacc[jf], 0, 0, 0);
            }
        }

        // online softmax, deferred rescale: keep m_run unless max grew by >3
        float tmax = sacc[0][0];
        #pragma unroll
        for (int jf = 0; jf < 4; ++jf)
            #pragma unroll
            for (int r = 0; r < 4; ++r) tmax = fmaxf(tmax, sacc[jf][r]);
        tmax = fmaxf(tmax, __shfl_xor(tmax, 16));
        tmax = fmaxf(tmax, __shfl_xor(tmax, 32));
        if (__any(tmax > m_run + 3.0f)) {
            const float mnew = fmaxf(m_run, tmax);
            const float fac = fast_exp2(m_run - mnew);
            m_run = mnew;
            l_run *= fac;
            #pragma unroll
            for (int r = 0; r < 4; ++r) {
                float fr = __shfl(fac, 4 * g + r, 16);
                #pragma unroll
                for (int df = 0; df < 4; ++df) oacc[df][r] *= fr;
            }
        }
        float lsum = 0.f;
        #pragma unroll
        for (int jf = 0; jf < 4; ++jf) {
            #pragma unroll
            for (int r = 0; r < 4; ++r) {
                float e = fast_exp2(sacc[jf][r] - m_run);
                sacc[jf][r] = e;  // keep for packing
                lsum += e;
            }
        }
        lsum += __shfl_xor(lsum, 16);
        lsum += __shfl_xor(lsum, 32);
        l_run += lsum;

        // P -> frag-major per-wave LDS tile (packed pairs, 2 insts / 4 elems)
        #pragma unroll
        for (int jf = 0; jf < 4; ++jf) {
            uint2 wpk;
            wpk.x = cvt_pk_bf16(sacc[jf][0], sacc[jf][1]);
            wpk.y = cvt_pk_bf16(sacc[jf][2], sacc[jf][3]);
            *(uint2*)(Pw + (jf >> 1) * 512 +
                      (((jf & 1) * 2 + (g >> 1)) * 16 + p) * 8 + (g & 1) * 4) =
                wpk;
        }
        asm volatile("s_waitcnt lgkmcnt(0)" ::: "memory");
        __builtin_amdgcn_sched_barrier(0);

        // PV: oacc += P * V (B-frags from V^T tile)
        #pragma unroll
        for (int ks = 0; ks < 2; ++ks) {
            bf16x8 aP = *(const bf16x8*)(Pw + ks * 512 + lane * 8);
            #pragma unroll
            for (int df = 0; df < 4; ++df) {
                bf16x8 bV =
                    *(const bf16x8*)(Vc + df * 1024 + ks * 512 + lane * 8);
                oacc[df] = __builtin_amdgcn_mfma_f32_16x16x32_bf16(
                    aP, bV, oacc[df], 0, 0, 0);
            }
        }
    }

    const float inv = 1.f / l_run;  // lane's q = p
    const int b = bh / HH, h = bh % HH;
    #pragma unroll
    for (int r = 0; r < 4; ++r) {
        float ir = __shfl(inv, 4 * g + r, 16);
        int n = q0 + w * 16 + 4 * g + r;
        #pragma unroll
        for (int df = 0; df < 4; ++df) {
            float v = oacc[df][r] * ir;
            unsigned short hi = f2bf(v);
            unsigned short lo = f2bf(v - bf2f(hi));
            size_t off = ((size_t)(b * NN + n)) * CC + h * HD + df * 16 + p;
            aoh[off] = (short)hi;
            aol[off] = (short)lo;
        }
    }
}

// ---------------------------------------------------------------------------
// gemm_proj (split-bf16, 3-MFMA): counted-wait ring-2 pipeline, 64KB LDS
// -> 2 blocks/CU. out = ao @ We_p + bp  (fp32 out)
// ---------------------------------------------------------------------------
__device__ __forceinline__ void stage_split(const short* __restrict__ gAh,
                                            const short* __restrict__ gAl,
                                            const short* __restrict__ gBh,
                                            const short* __restrict__ gBl,
                                            int rowA0, int rowB0, int kt,
                                            short* Lb, int tid) {
    const int fr = ((tid >> 6) << 4) | (tid & 15);
    const int kc = ((tid >> 4) & 3) * 8 + kt;
    const size_t ga0 = (size_t)(rowA0 + fr) * CC + kc;
    const size_t ga1 = ga0 + (size_t)64 * CC;
    const size_t gb0 = (size_t)(rowB0 + fr) * CC + kc;
    const size_t gb1 = gb0 + (size_t)64 * CC;
    short* d0 = Lb + tid * 8;
    short* d1 = Lb + (tid + 256) * 8;
    gload16(gAh + ga0, d0);
    gload16(gAh + ga1, d1);
    gload16(gAl + ga0, d0 + 4096);
    gload16(gAl + ga1, d1 + 4096);
    gload16(gBh + gb0, d0 + 8192);
    gload16(gBh + gb1, d1 + 8192);
    gload16(gBl + gb0, d0 + 12288);
    gload16(gBl + gb1, d1 + 12288);
}

__global__ __launch_bounds__(256, 2) void gemm_proj(
    const short* __restrict__ aoh, const short* __restrict__ aol,
    const short* __restrict__ wth, const short* __restrict__ wtl,
    const float* __restrict__ bp, float* __restrict__ out) {
    __shared__ __align__(16) short L[2][4 * 4096];  // 2 x 32 KiB

    int flat = blockIdx.x + 6 * blockIdx.y;  // 384 wgs
    int swz = (flat & 7) * 48 + (flat >> 3);
    int by = swz / 6, bx = swz - by * 6;
    const int m0 = by * 128, c0 = bx * 128;

    const short* wph = wth + (size_t)3 * WSZ;
    const short* wpl = wtl + (size_t)3 * WSZ;

    f32x4 acc[4][4];
    const f32x4 z4 = {0.f, 0.f, 0.f, 0.f};
    #pragma unroll
    for (int i = 0; i < 4; ++i)
        #pragma unroll
        for (int j = 0; j < 4; ++j) acc[i][j] = z4;

    const int tid = threadIdx.x, lane = tid & 63, w = tid >> 6;
    const int wm = w >> 1, wn = w & 1, p = lane & 15, g = lane >> 4;

    stage_split(aoh, aol, wph, wpl, m0, c0, 0, L[0], tid);
    for (int ki = 0; ki < 24; ++ki) {
        wait_vm0_barrier();  // tile ki ready; buf (ki-1)&1 free
        if (ki < 23)
            stage_split(aoh, aol, wph, wpl, m0, c0, (ki + 1) * 32,
                        L[(ki + 1) & 1], tid);  // overlaps this tile's MFMAs
        const short* Lb = L[ki & 1];
        const int fb = lane * 8;
        bf16x8 ah[4], al[4], bh[4], bl[4];
        #pragma unroll
        for (int i = 0; i < 4; ++i) {
            ah[i] = *(const bf16x8*)(Lb + (wm * 4 + i) * 512 + fb);
            al[i] = *(const bf16x8*)(Lb + 4096 + (wm * 4 + i) * 512 + fb);
        }
        #pragma unroll
        for (int j = 0; j < 4; ++j) {
            bh[j] = *(const bf16x8*)(Lb + 8192 + (wn * 4 + j) * 512 + fb);
            bl[j] = *(const bf16x8*)(Lb + 12288 + (wn * 4 + j) * 512 + fb);
        }
        #pragma unroll
        for (int i = 0; i < 4; ++i) {
            #pragma unroll
            for (int j = 0; j < 4; ++j) {
                acc[i][j] = __builtin_amdgcn_mfma_f32_16x16x32_bf16(
                    ah[i], bh[j], acc[i][j], 0, 0, 0);
                acc[i][j] = __builtin_amdgcn_mfma_f32_16x16x32_bf16(
                    ah[i], bl[j], acc[i][j], 0, 0, 0);
                acc[i][j] = __builtin_amdgcn_mfma_f32_16x16x32_bf16(
                    al[i], bh[j], acc[i][j], 0, 0, 0);
            }
        }
    }

    float bpv[4];
    #pragma unroll
    for (int j = 0; j < 4; ++j) bpv[j] = bp[c0 + wn * 64 + j * 16 + p];

    #pragma unroll
    for (int i = 0; i < 4; ++i) {
        #pragma unroll
        for (int r = 0; r < 4; ++r) {
            int m = m0 + wm * 64 + i * 16 + 4 * g + r;
            #pragma unroll
            for (int j = 0; j < 4; ++j) {
                int c = c0 + wn * 64 + j * 16 + p;
                out[(size_t)m * CC + c] = acc[i][j][r] + bpv[j];
            }
        }
    }
}

// ---------------------------------------------------------------------------
extern "C" void kernel_launch(void* const* d_in, const int* in_sizes, int n_in,
                              void* d_out, int out_size, void* d_ws,
                              size_t ws_size, hipStream_t stream) {
    const float* x = (const float*)d_in[0];
    const float* Wq = (const float*)d_in[1];
    const float* Wk = (const float*)d_in[2];
    const float* Wv = (const float*)d_in[3];
    const float* Wp = (const float*)d_in[4];
    const float* bp = (const float*)d_in[5];
    const float* la_q = (const float*)d_in[6];
    const float* lb_q = (const float*)d_in[7];
    const float* la_k = (const float*)d_in[8];
    const float* lb_k = (const float*)d_in[9];
    const float* la_v = (const float*)d_in[10];
    const float* lb_v = (const float*)d_in[11];
    const float* bw = (const float*)d_in[12];
    float* out = (float*)d_out;

    short* ws = (short*)d_ws;
    short* wt_hi = ws;                       // 4*WSZ
    short* wt_lo = wt_hi + (size_t)4 * WSZ;  // 4*WSZ
    short* x_hi = wt_lo + (size_t)4 * WSZ;   // MM*CC
    short* qbuf = x_hi + (size_t)MM * CC;    // [B,H,N,HD]
    short* kbuf = qbuf + (size_t)MM * CC;
    short* vtbuf = kbuf + (size_t)MM * CC;   // [B,H,HD,N]
    short* aoh = vtbuf + (size_t)MM * CC;    // [B,N,C] hi
    short* aol = aoh + (size_t)MM * CC;      // [B,N,C] lo

    prep_w<<<dim3(CC / 64, CC / 64, 4), 256, 0, stream>>>(
        Wq, Wk, Wv, Wp, la_q, lb_q, la_k, lb_k, la_v, lb_v, bw, wt_hi, wt_lo);
    prep_cvt<<<2048, 256, 0, stream>>>(x, x_hi, MM * CC / 4);
    gemm_qkv_fused<<<dim3(CC / 128, MM / 128), 256, 0, stream>>>(
        x_hi, wt_hi, qbuf, kbuf, vtbuf);
    attn<<<dim3(NN / 64, BB * HH), 256, 0, stream>>>(qbuf, kbuf, vtbuf, aoh, aol);
    gemm_proj<<<dim3(CC / 128, MM / 128), 256, 0, stream>>>(aoh, aol, wt_hi,
                                                            wt_lo, bp, out);
}